// Round 9
// baseline (198.036 us; speedup 1.0000x reference)
//
#include <hip/hip_runtime.h>

#define H 16
#define N 2048
#define E 64
#define D 1024

typedef __attribute__((ext_vector_type(8))) short bf16x8;
typedef __attribute__((ext_vector_type(8))) _Float16 f16x8;
typedef __attribute__((ext_vector_type(2))) __fp16 fp16v2;
typedef __attribute__((ext_vector_type(4))) float f32x4;

__device__ __forceinline__ float bf2f(unsigned short u) {
    union { unsigned int i; float f; } v;
    v.i = ((unsigned int)u) << 16;
    return v.f;
}
__device__ __forceinline__ unsigned short f2bf(float f) {
    unsigned int u = __float_as_uint(f);
    return (unsigned short)((u + 0x7fffu + ((u >> 16) & 1u)) >> 16);
}
#define MFMA(a, b, c)  __builtin_amdgcn_mfma_f32_16x16x32_bf16(a, b, c, 0, 0, 0)
#define MFMAH(a, b, c) __builtin_amdgcn_mfma_f32_16x16x32_f16(a, b, c, 0, 0, 0)

// async global->LDS, 16B per lane. LDS dest must be base+lane*16 contiguous.
typedef __attribute__((address_space(3))) unsigned int lds_u32;
typedef const __attribute__((address_space(1))) unsigned int glb_u32;
__device__ __forceinline__ void dma16(const unsigned short* g, unsigned short* l) {
    __builtin_amdgcn_global_load_lds((glb_u32*)g, (lds_u32*)l, 16, 0, 0);
}

// XOR-swizzled LDS tiles (16B chunk granularity): physical chunk = c ^ (row&7).
__device__ __forceinline__ int sw8(int row, int c)  { return row * 64  + ((c ^ (row & 7)) << 3); }

// ---------------------------------------------------------------------------
// K1: merged converts. blocks [0,2048): x fp32 -> xh/xl.
// blocks [2048,3072): weights. q -> wBh/wBl rows [0,1024); k -> rows
// [1024,2048); v -> wvt [h*64+e][d] (hi only); o -> woh [c][d] (hi only).
// ---------------------------------------------------------------------------
__global__ __launch_bounds__(256) void convert_all_kernel(
    const float* __restrict__ x,
    const float* __restrict__ qw, const float* __restrict__ kw,
    const float* __restrict__ vw, const float* __restrict__ ow,
    unsigned short* __restrict__ xh, unsigned short* __restrict__ xl,
    unsigned short* __restrict__ wBh, unsigned short* __restrict__ wBl,
    unsigned short* __restrict__ wvt, unsigned short* __restrict__ woh)
{
    __shared__ float ts[64][65];
    const int b0 = blockIdx.x;
    const int t = threadIdx.x;
    if (b0 < 2048) {
        const int i = (b0 * 256 + t) * 4;
        const float4 v = *(const float4*)&x[i];
        ushort4 hh, ll;
        hh.x = f2bf(v.x); ll.x = f2bf(v.x - bf2f(hh.x));
        hh.y = f2bf(v.y); ll.y = f2bf(v.y - bf2f(hh.y));
        hh.z = f2bf(v.z); ll.z = f2bf(v.z - bf2f(hh.z));
        hh.w = f2bf(v.w); ll.w = f2bf(v.w - bf2f(hh.w));
        *(ushort4*)&xh[i] = hh;
        *(ushort4*)&xl[i] = ll;
        return;
    }
    const int b = b0 - 2048;
    const float* src;
    int rs, dt, orow0;
    bool has_lo;
    unsigned short *dh, *dl;
    if (b < 768) {
        const int which = b >> 8, r = b & 255, h = r >> 4;
        dt = r & 15;
        src = (which == 0 ? qw : which == 1 ? kw : vw) + ((size_t)h * D + dt * 64) * E;
        rs = E;
        if (which == 0)      { dh = wBh; dl = wBl; orow0 = h * 64;        has_lo = true; }
        else if (which == 1) { dh = wBh; dl = wBl; orow0 = 1024 + h * 64; has_lo = true; }
        else                 { dh = wvt; dl = wBl; orow0 = h * 64;        has_lo = false; }
    } else {
        const int r = b - 768, ct = r >> 4;
        dt = r & 15;
        src = ow + (size_t)(dt * 64) * D + ct * 64;
        rs = D;
        orow0 = ct * 64;
        dh = woh; dl = wBl; has_lo = false;   // o: hi only
    }
    {
        const int row = t >> 2, cb = (t & 3) * 16;
        #pragma unroll
        for (int j = 0; j < 16; j += 4) {
            const float4 v = *(const float4*)&src[row * rs + cb + j];
            ts[row][cb + j + 0] = v.x;
            ts[row][cb + j + 1] = v.y;
            ts[row][cb + j + 2] = v.z;
            ts[row][cb + j + 3] = v.w;
        }
    }
    __syncthreads();
    {
        const int cl = t >> 2, dp = (t & 3) * 16;
        bf16x8 hv0, hv1, lv0, lv1;
        #pragma unroll
        for (int i = 0; i < 16; ++i) {
            const float f = ts[dp + i][cl];
            const unsigned short hh = f2bf(f);
            const unsigned short lo = f2bf(f - bf2f(hh));
            if (i < 8) { hv0[i] = (short)hh; lv0[i] = (short)lo; }
            else       { hv1[i - 8] = (short)hh; lv1[i - 8] = (short)lo; }
        }
        const size_t o = (size_t)(orow0 + cl) * D + dt * 64 + dp;
        *(bf16x8*)&dh[o] = hv0;
        *(bf16x8*)&dh[o + 8] = hv1;
        if (has_lo) {
            *(bf16x8*)&dl[o] = lv0;
            *(bf16x8*)&dl[o + 8] = lv1;
        }
    }
}

// ---------------------------------------------------------------------------
// K2: QKV projection. grid (16 Mtiles, 48 col-tiles); 128x64 tiles, BK=64.
// [0,16)=Q, [16,32)=K, [32,48)=V. Q scaled by 0.125*log2(e) (base-2 softmax).
// Vt output is fp16 [h*64+e][n].
// ---------------------------------------------------------------------------
__global__ __launch_bounds__(256, 3) void qkv_kernel(
    const unsigned short* __restrict__ xh, const unsigned short* __restrict__ xl,
    const unsigned short* __restrict__ wBh, const unsigned short* __restrict__ wBl,
    const unsigned short* __restrict__ wvt,
    unsigned short* __restrict__ Qh, unsigned short* __restrict__ Ql,
    unsigned short* __restrict__ Kh, unsigned short* __restrict__ Kl,
    unsigned short* __restrict__ Vt)
{
    __shared__ unsigned short ash[128 * 64], asl[128 * 64];
    __shared__ unsigned short bsh[64 * 64], bsl[64 * 64];
    const int n0 = blockIdx.x * 128;
    const int ct0 = blockIdx.y;
    const int sec = ct0 >> 4;            // 0=Q 1=K 2=V
    const int hh = ct0 & 15;
    const bool isv = (sec == 2);
    const unsigned short* Bh = isv ? wvt : wBh;
    const size_t brow0 = (sec == 1 ? 1024 : 0) + hh * 64;

    const int t = threadIdx.x;
    const int lane = t & 63, wvi = t >> 6, quad = lane >> 4, l15 = lane & 15;

    f32x4 acc[2][4];
    #pragma unroll
    for (int i = 0; i < 2; ++i)
        #pragma unroll
        for (int j = 0; j < 4; ++j) acc[i][j] = (f32x4){0.f, 0.f, 0.f, 0.f};

    for (int k0 = 0; k0 < D; k0 += 64) {
        __syncthreads();
        #pragma unroll
        for (int p = 0; p < 4; ++p) {
            const int row = p * 32 + wvi * 8 + (lane >> 3);
            const int lc = (lane & 7) ^ (row & 7);
            const int lo = p * 2048 + wvi * 512 + lane * 8;
            const size_t ga = (size_t)(n0 + row) * D + k0 + lc * 8;
            dma16(&xh[ga], &ash[lo]);
            if (!isv) dma16(&xl[ga], &asl[lo]);
        }
        #pragma unroll
        for (int p = 0; p < 2; ++p) {
            const int row = p * 32 + wvi * 8 + (lane >> 3);
            const int lc = (lane & 7) ^ (row & 7);
            const int lo = p * 2048 + wvi * 512 + lane * 8;
            const size_t gb = (brow0 + row) * D + k0 + lc * 8;
            dma16(&Bh[gb], &bsh[lo]);
            if (!isv) dma16(&wBl[gb], &bsl[lo]);
        }
        __syncthreads();

        #pragma unroll
        for (int kwi = 0; kwi < 2; ++kwi) {
            const int c = kwi * 4 + quad;
            bf16x8 ah[2], al[2], bh[4], bl[4];
            #pragma unroll
            for (int i = 0; i < 2; ++i) {
                ah[i] = *(const bf16x8*)&ash[sw8(wvi * 32 + i * 16 + l15, c)];
                if (!isv) al[i] = *(const bf16x8*)&asl[sw8(wvi * 32 + i * 16 + l15, c)];
            }
            #pragma unroll
            for (int j = 0; j < 4; ++j) {
                bh[j] = *(const bf16x8*)&bsh[sw8(j * 16 + l15, c)];
                if (!isv) bl[j] = *(const bf16x8*)&bsl[sw8(j * 16 + l15, c)];
            }
            #pragma unroll
            for (int i = 0; i < 2; ++i)
                #pragma unroll
                for (int j = 0; j < 4; ++j) {
                    acc[i][j] = MFMA(ah[i], bh[j], acc[i][j]);
                    if (!isv) {
                        acc[i][j] = MFMA(ah[i], bl[j], acc[i][j]);
                        acc[i][j] = MFMA(al[i], bh[j], acc[i][j]);
                    }
                }
        }
    }

    if (isv) {
        #pragma unroll
        for (int j = 0; j < 4; ++j) {
            const int e = j * 16 + l15;
            #pragma unroll
            for (int i = 0; i < 2; ++i) {
                const int nb = n0 + wvi * 32 + i * 16 + quad * 4;
                union { fp16v2 h; unsigned int u; } c01, c23;
                c01.h = __builtin_amdgcn_cvt_pkrtz(acc[i][j][0], acc[i][j][1]);
                c23.h = __builtin_amdgcn_cvt_pkrtz(acc[i][j][2], acc[i][j][3]);
                uint2 pk = {c01.u, c23.u};
                *(uint2*)&Vt[((size_t)hh * 64 + e) * N + nb] = pk;
            }
        }
    } else {
        // Q: fold 0.125 (1/sqrt(64)) * log2(e) so softmax runs in base 2.
        const float scale = (sec == 0) ? 0.125f * 1.44269504f : 1.0f;
        unsigned short* Oh = (sec == 0) ? Qh : Kh;
        unsigned short* Ol = (sec == 0) ? Ql : Kl;
        #pragma unroll
        for (int j = 0; j < 4; ++j) {
            const int e = j * 16 + l15;
            #pragma unroll
            for (int i = 0; i < 2; ++i)
                #pragma unroll
                for (int r = 0; r < 4; ++r) {
                    const int n = n0 + wvi * 32 + i * 16 + quad * 4 + r;
                    const float val = acc[i][j][r] * scale;
                    const unsigned short hv = f2bf(val);
                    Oh[((size_t)hh * N + n) * E + e] = hv;
                    Ol[((size_t)hh * N + n) * E + e] = f2bf(val - bf2f(hv));
                }
        }
    }
}

// ---------------------------------------------------------------------------
// K3: flash attention, double-buffered DMA staging, 64-key tiles, fp16 PV.
// grid (32, 16); block 256 = 4 waves x 16 Q-rows. Softmax in base 2.
// ---------------------------------------------------------------------------
__global__ __launch_bounds__(256, 2) void attn_kernel(
    const unsigned short* __restrict__ Qh, const unsigned short* __restrict__ Ql,
    const unsigned short* __restrict__ Kh, const unsigned short* __restrict__ Kl,
    const unsigned short* __restrict__ Vt,   // fp16
    unsigned short* __restrict__ Ch)
{
    __shared__ unsigned short kb[2][3][64 * 64];   // [buf][{Kh,Kl,V}] 48 KB
    __shared__ unsigned short ps[4 * 16 * 72];     // per-wave fp16 P, 9.2 KB
    const int r0 = blockIdx.x * 64, h = blockIdx.y;
    const int t = threadIdx.x, lane = t & 63, wvi = t >> 6, quad = lane >> 4, l15 = lane & 15;

    // staging pattern (64 rows x 64 shorts per plane, 2 passes of 32 rows)
    const int srow0 = wvi * 8 + (lane >> 3);
    const int slo0  = wvi * 512 + lane * 8;

    bf16x8 qfh[2], qfl[2];
    {
        const size_t base = ((size_t)h * N + r0 + wvi * 16 + l15) * E;
        #pragma unroll
        for (int kwi = 0; kwi < 2; ++kwi) {
            qfh[kwi] = *(const bf16x8*)&Qh[base + kwi * 32 + quad * 8];
            qfl[kwi] = *(const bf16x8*)&Ql[base + kwi * 32 + quad * 8];
        }
    }

    f32x4 oacc[4];
    #pragma unroll
    for (int ct = 0; ct < 4; ++ct) oacc[ct] = (f32x4){0.f, 0.f, 0.f, 0.f};
    float mrow[4] = {-1e30f, -1e30f, -1e30f, -1e30f};
    float lrow[4] = {0.f, 0.f, 0.f, 0.f};

    // prologue: stage tile 0 into buffer 0
    #pragma unroll
    for (int p = 0; p < 2; ++p) {
        const int row = p * 32 + srow0;
        const int lc = (lane & 7) ^ (row & 7);
        const int lo = p * 2048 + slo0;
        const size_t gk = ((size_t)h * N + row) * E + lc * 8;
        dma16(&Kh[gk], &kb[0][0][lo]);
        dma16(&Kl[gk], &kb[0][1][lo]);
        dma16(&Vt[((size_t)h * 64 + row) * N + lc * 8], &kb[0][2][lo]);
    }

    for (int mt = 0; mt < N / 64; ++mt) {
        const int b = mt & 1;
        __syncthreads();   // staged(buf b) landed; prior reads of buf 1-b done
        if (mt + 1 < N / 64) {
            const int m1 = (mt + 1) * 64;
            #pragma unroll
            for (int p = 0; p < 2; ++p) {
                const int row = p * 32 + srow0;
                const int lc = (lane & 7) ^ (row & 7);
                const int lo = p * 2048 + slo0;
                const size_t gk = ((size_t)h * N + m1 + row) * E + lc * 8;
                dma16(&Kh[gk], &kb[1 - b][0][lo]);
                dma16(&Kl[gk], &kb[1 - b][1][lo]);
                dma16(&Vt[((size_t)h * 64 + row) * N + m1 + lc * 8], &kb[1 - b][2][lo]);
            }
        }

        // S = Q K^T (log2-domain scale folded into Q)
        f32x4 s[4];
        #pragma unroll
        for (int ct = 0; ct < 4; ++ct) s[ct] = (f32x4){0.f, 0.f, 0.f, 0.f};
        #pragma unroll
        for (int kwi = 0; kwi < 2; ++kwi) {
            const int c = kwi * 4 + quad;
            #pragma unroll
            for (int ct = 0; ct < 4; ++ct) {
                const bf16x8 bh = *(const bf16x8*)&kb[b][0][sw8(ct * 16 + l15, c)];
                const bf16x8 bl = *(const bf16x8*)&kb[b][1][sw8(ct * 16 + l15, c)];
                s[ct] = MFMA(qfh[kwi], bh, s[ct]);
                s[ct] = MFMA(qfh[kwi], bl, s[ct]);
                s[ct] = MFMA(qfl[kwi], bh, s[ct]);
            }
        }

        // online softmax, base 2
        #pragma unroll
        for (int r = 0; r < 4; ++r) {
            float mx = fmaxf(fmaxf(s[0][r], s[1][r]), fmaxf(s[2][r], s[3][r]));
            mx = fmaxf(mx, __shfl_xor(mx, 1));
            mx = fmaxf(mx, __shfl_xor(mx, 2));
            mx = fmaxf(mx, __shfl_xor(mx, 4));
            mx = fmaxf(mx, __shfl_xor(mx, 8));
            const float mn = fmaxf(mrow[r], mx);
            const float alpha = exp2f(mrow[r] - mn);
            mrow[r] = mn;
            float sum = 0.f;
            #pragma unroll
            for (int ct = 0; ct < 4; ++ct) {
                const float p = exp2f(s[ct][r] - mn);
                s[ct][r] = p;
                sum += p;
            }
            sum += __shfl_xor(sum, 1);
            sum += __shfl_xor(sum, 2);
            sum += __shfl_xor(sum, 4);
            sum += __shfl_xor(sum, 8);
            lrow[r] = lrow[r] * alpha + sum;
            #pragma unroll
            for (int ct = 0; ct < 4; ++ct) oacc[ct][r] *= alpha;
        }

        // P -> wave-private LDS as fp16 (C-layout -> A-layout)
        #pragma unroll
        for (int ct = 0; ct < 4; ++ct)
            #pragma unroll
            for (int r = 0; r < 4; ++r) {
                union { _Float16 h; unsigned short u; } cv;
                cv.h = (_Float16)s[ct][r];
                ps[(wvi * 16 + quad * 4 + r) * 72 + ct * 16 + l15] = cv.u;
            }

        // O += P V (fp16 MFMA)
        #pragma unroll
        for (int kwi = 0; kwi < 2; ++kwi) {
            const f16x8 pa = *(const f16x8*)&ps[(wvi * 16 + l15) * 72 + kwi * 32 + quad * 8];
            #pragma unroll
            for (int ct = 0; ct < 4; ++ct) {
                const f16x8 vb = *(const f16x8*)&kb[b][2][sw8(ct * 16 + l15, kwi * 4 + quad)];
                oacc[ct] = MFMAH(pa, vb, oacc[ct]);
            }
        }
    }

    #pragma unroll
    for (int r = 0; r < 4; ++r) {
        const float inv = 1.f / lrow[r];
        const int n = r0 + wvi * 16 + quad * 4 + r;
        #pragma unroll
        for (int ct = 0; ct < 4; ++ct)
            Ch[(size_t)n * D + h * 64 + ct * 16 + l15] = f2bf(oacc[ct][r] * inv);
    }
}

// ---------------------------------------------------------------------------
// K4: out = ctx @ Wo, single-term bf16. grid (32, 16); tile 64x64, BK=64.
// ---------------------------------------------------------------------------
__global__ __launch_bounds__(256, 4) void out_proj_kernel(
    const unsigned short* __restrict__ Chh, const unsigned short* __restrict__ Wh,
    float* __restrict__ out)
{
    __shared__ unsigned short ash[64 * 64], bsh[64 * 64];
    const int n0 = blockIdx.x * 64, c0 = blockIdx.y * 64;
    const int t = threadIdx.x, lane = t & 63, wvi = t >> 6, quad = lane >> 4, l15 = lane & 15;

    f32x4 acc[4];
    #pragma unroll
    for (int j = 0; j < 4; ++j) acc[j] = (f32x4){0.f, 0.f, 0.f, 0.f};

    for (int k0 = 0; k0 < D; k0 += 64) {
        __syncthreads();
        #pragma unroll
        for (int p = 0; p < 2; ++p) {
            const int row = p * 32 + wvi * 8 + (lane >> 3);
            const int lc = (lane & 7) ^ (row & 7);
            const int lo = p * 2048 + wvi * 512 + lane * 8;
            dma16(&Chh[(size_t)(n0 + row) * D + k0 + lc * 8], &ash[lo]);
            dma16(&Wh[(size_t)(c0 + row) * D + k0 + lc * 8], &bsh[lo]);
        }
        __syncthreads();

        #pragma unroll
        for (int kwi = 0; kwi < 2; ++kwi) {
            const int c = kwi * 4 + quad;
            const bf16x8 ah = *(const bf16x8*)&ash[sw8(wvi * 16 + l15, c)];
            #pragma unroll
            for (int j = 0; j < 4; ++j) {
                const bf16x8 bh = *(const bf16x8*)&bsh[sw8(j * 16 + l15, c)];
                acc[j] = MFMA(ah, bh, acc[j]);
            }
        }
    }

    #pragma unroll
    for (int r = 0; r < 4; ++r) {
        const int n = n0 + wvi * 16 + quad * 4 + r;
        #pragma unroll
        for (int j = 0; j < 4; ++j)
            out[(size_t)n * D + c0 + j * 16 + l15] = acc[j][r];
    }
}

// ---------------------------------------------------------------------------
extern "C" void kernel_launch(void* const* d_in, const int* in_sizes, int n_in,
                              void* d_out, int out_size, void* d_ws, size_t ws_size,
                              hipStream_t stream) {
    const float* x  = (const float*)d_in[0];
    const float* qw = (const float*)d_in[1];
    const float* kw = (const float*)d_in[2];
    const float* vw = (const float*)d_in[3];
    const float* ow = (const float*)d_in[4];
    float* out = (float*)d_out;

    unsigned short* ws = (unsigned short*)d_ws;
    const size_t M1 = 1024 * 1024;
    unsigned short* wBh = ws;                 // [2048][1024] = 2M shorts
    unsigned short* wBl = ws + 2 * M1;
    unsigned short* wvt = ws + 4 * M1;        // [1024][1024] = 1M
    unsigned short* woh = ws + 5 * M1;
    unsigned short* xh  = ws + 6 * M1;        // [2048][1024] = 2M
    unsigned short* xl  = ws + 8 * M1;
    unsigned short* Qh  = ws + 10 * M1;       // [h][n][e] = 2M each
    unsigned short* Ql  = ws + 12 * M1;
    unsigned short* Kh  = ws + 14 * M1;
    unsigned short* Kl  = ws + 16 * M1;
    unsigned short* Vt  = ws + 18 * M1;       // fp16 [h*64+e][n] = 2M
    unsigned short* Ch  = xh;                 // alias: x dead after qkv

    convert_all_kernel<<<3072, 256, 0, stream>>>(x, qw, kw, vw, ow,
                                                 xh, xl, wBh, wBl, wvt, woh);
    qkv_kernel<<<dim3(16, 48), 256, 0, stream>>>(xh, xl, wBh, wBl, wvt,
                                                 Qh, Ql, Kh, Kl, Vt);
    attn_kernel<<<dim3(32, 16), 256, 0, stream>>>(Qh, Ql, Kh, Kl, Vt, Ch);
    out_proj_kernel<<<dim3(32, 16), 256, 0, stream>>>(Ch, woh, out);
}

// Round 10
// 191.658 us; speedup vs baseline: 1.0333x; 1.0333x over previous
//
#include <hip/hip_runtime.h>

#define H 16
#define N 2048
#define E 64
#define D 1024

typedef __attribute__((ext_vector_type(8))) short bf16x8;
typedef __attribute__((ext_vector_type(8))) _Float16 f16x8;
typedef __attribute__((ext_vector_type(2))) __fp16 fp16v2;
typedef __attribute__((ext_vector_type(4))) float f32x4;

__device__ __forceinline__ float bf2f(unsigned short u) {
    union { unsigned int i; float f; } v;
    v.i = ((unsigned int)u) << 16;
    return v.f;
}
__device__ __forceinline__ unsigned short f2bf(float f) {
    unsigned int u = __float_as_uint(f);
    return (unsigned short)((u + 0x7fffu + ((u >> 16) & 1u)) >> 16);
}
#define MFMA(a, b, c)  __builtin_amdgcn_mfma_f32_16x16x32_bf16(a, b, c, 0, 0, 0)
#define MFMAH(a, b, c) __builtin_amdgcn_mfma_f32_16x16x32_f16(a, b, c, 0, 0, 0)

// async global->LDS, 16B per lane. LDS dest must be base+lane*16 contiguous.
typedef __attribute__((address_space(3))) unsigned int lds_u32;
typedef const __attribute__((address_space(1))) unsigned int glb_u32;
__device__ __forceinline__ void dma16(const unsigned short* g, unsigned short* l) {
    __builtin_amdgcn_global_load_lds((glb_u32*)g, (lds_u32*)l, 16, 0, 0);
}

// XOR-swizzled LDS tiles (16B chunk granularity): physical chunk = c ^ (row&7).
__device__ __forceinline__ int sw8(int row, int c)  { return row * 64  + ((c ^ (row & 7)) << 3); }
__device__ __forceinline__ int sw16(int row, int c) { return row * 128 + ((c ^ (row & 7)) << 3); }

// ---------------------------------------------------------------------------
// K1: merged converts. blocks [0,2048): x fp32 -> xh/xl.
// blocks [2048,3072): weights. q -> wBh/wBl rows [0,1024); k -> rows
// [1024,2048); v -> wvt [h*64+e][d] (hi only); o -> woh [c][d] (hi only).
// ---------------------------------------------------------------------------
__global__ __launch_bounds__(256) void convert_all_kernel(
    const float* __restrict__ x,
    const float* __restrict__ qw, const float* __restrict__ kw,
    const float* __restrict__ vw, const float* __restrict__ ow,
    unsigned short* __restrict__ xh, unsigned short* __restrict__ xl,
    unsigned short* __restrict__ wBh, unsigned short* __restrict__ wBl,
    unsigned short* __restrict__ wvt, unsigned short* __restrict__ woh)
{
    __shared__ float ts[64][65];
    const int b0 = blockIdx.x;
    const int t = threadIdx.x;
    if (b0 < 2048) {
        const int i = (b0 * 256 + t) * 4;
        const float4 v = *(const float4*)&x[i];
        ushort4 hh, ll;
        hh.x = f2bf(v.x); ll.x = f2bf(v.x - bf2f(hh.x));
        hh.y = f2bf(v.y); ll.y = f2bf(v.y - bf2f(hh.y));
        hh.z = f2bf(v.z); ll.z = f2bf(v.z - bf2f(hh.z));
        hh.w = f2bf(v.w); ll.w = f2bf(v.w - bf2f(hh.w));
        *(ushort4*)&xh[i] = hh;
        *(ushort4*)&xl[i] = ll;
        return;
    }
    const int b = b0 - 2048;
    const float* src;
    int rs, dt, orow0;
    bool has_lo;
    unsigned short *dh, *dl;
    if (b < 768) {
        const int which = b >> 8, r = b & 255, h = r >> 4;
        dt = r & 15;
        src = (which == 0 ? qw : which == 1 ? kw : vw) + ((size_t)h * D + dt * 64) * E;
        rs = E;
        if (which == 0)      { dh = wBh; dl = wBl; orow0 = h * 64;        has_lo = true; }
        else if (which == 1) { dh = wBh; dl = wBl; orow0 = 1024 + h * 64; has_lo = true; }
        else                 { dh = wvt; dl = wBl; orow0 = h * 64;        has_lo = false; }
    } else {
        const int r = b - 768, ct = r >> 4;
        dt = r & 15;
        src = ow + (size_t)(dt * 64) * D + ct * 64;
        rs = D;
        orow0 = ct * 64;
        dh = woh; dl = wBl; has_lo = false;   // o: hi only
    }
    {
        const int row = t >> 2, cb = (t & 3) * 16;
        #pragma unroll
        for (int j = 0; j < 16; j += 4) {
            const float4 v = *(const float4*)&src[row * rs + cb + j];
            ts[row][cb + j + 0] = v.x;
            ts[row][cb + j + 1] = v.y;
            ts[row][cb + j + 2] = v.z;
            ts[row][cb + j + 3] = v.w;
        }
    }
    __syncthreads();
    {
        const int cl = t >> 2, dp = (t & 3) * 16;
        bf16x8 hv0, hv1, lv0, lv1;
        #pragma unroll
        for (int i = 0; i < 16; ++i) {
            const float f = ts[dp + i][cl];
            const unsigned short hh = f2bf(f);
            const unsigned short lo = f2bf(f - bf2f(hh));
            if (i < 8) { hv0[i] = (short)hh; lv0[i] = (short)lo; }
            else       { hv1[i - 8] = (short)hh; lv1[i - 8] = (short)lo; }
        }
        const size_t o = (size_t)(orow0 + cl) * D + dt * 64 + dp;
        *(bf16x8*)&dh[o] = hv0;
        *(bf16x8*)&dh[o + 8] = hv1;
        if (has_lo) {
            *(bf16x8*)&dl[o] = lv0;
            *(bf16x8*)&dl[o + 8] = lv1;
        }
    }
}

// ---------------------------------------------------------------------------
// K2: QKV projection. grid (16 Mtiles, 48 col-tiles); 128x64 tiles, BK=64.
// [0,16)=Q, [16,32)=K, [32,48)=V. Q scaled by 0.125*log2(e) (base-2 softmax).
// Vt output is fp16 [h*64+e][n].
// ---------------------------------------------------------------------------
__global__ __launch_bounds__(256, 3) void qkv_kernel(
    const unsigned short* __restrict__ xh, const unsigned short* __restrict__ xl,
    const unsigned short* __restrict__ wBh, const unsigned short* __restrict__ wBl,
    const unsigned short* __restrict__ wvt,
    unsigned short* __restrict__ Qh, unsigned short* __restrict__ Ql,
    unsigned short* __restrict__ Kh, unsigned short* __restrict__ Kl,
    unsigned short* __restrict__ Vt)
{
    __shared__ unsigned short ash[128 * 64], asl[128 * 64];
    __shared__ unsigned short bsh[64 * 64], bsl[64 * 64];
    const int n0 = blockIdx.x * 128;
    const int ct0 = blockIdx.y;
    const int sec = ct0 >> 4;            // 0=Q 1=K 2=V
    const int hh = ct0 & 15;
    const bool isv = (sec == 2);
    const unsigned short* Bh = isv ? wvt : wBh;
    const size_t brow0 = (sec == 1 ? 1024 : 0) + hh * 64;

    const int t = threadIdx.x;
    const int lane = t & 63, wvi = t >> 6, quad = lane >> 4, l15 = lane & 15;

    f32x4 acc[2][4];
    #pragma unroll
    for (int i = 0; i < 2; ++i)
        #pragma unroll
        for (int j = 0; j < 4; ++j) acc[i][j] = (f32x4){0.f, 0.f, 0.f, 0.f};

    for (int k0 = 0; k0 < D; k0 += 64) {
        __syncthreads();
        #pragma unroll
        for (int p = 0; p < 4; ++p) {
            const int row = p * 32 + wvi * 8 + (lane >> 3);
            const int lc = (lane & 7) ^ (row & 7);
            const int lo = p * 2048 + wvi * 512 + lane * 8;
            const size_t ga = (size_t)(n0 + row) * D + k0 + lc * 8;
            dma16(&xh[ga], &ash[lo]);
            if (!isv) dma16(&xl[ga], &asl[lo]);
        }
        #pragma unroll
        for (int p = 0; p < 2; ++p) {
            const int row = p * 32 + wvi * 8 + (lane >> 3);
            const int lc = (lane & 7) ^ (row & 7);
            const int lo = p * 2048 + wvi * 512 + lane * 8;
            const size_t gb = (brow0 + row) * D + k0 + lc * 8;
            dma16(&Bh[gb], &bsh[lo]);
            if (!isv) dma16(&wBl[gb], &bsl[lo]);
        }
        __syncthreads();

        #pragma unroll
        for (int kwi = 0; kwi < 2; ++kwi) {
            const int c = kwi * 4 + quad;
            bf16x8 ah[2], al[2], bh[4], bl[4];
            #pragma unroll
            for (int i = 0; i < 2; ++i) {
                ah[i] = *(const bf16x8*)&ash[sw8(wvi * 32 + i * 16 + l15, c)];
                if (!isv) al[i] = *(const bf16x8*)&asl[sw8(wvi * 32 + i * 16 + l15, c)];
            }
            #pragma unroll
            for (int j = 0; j < 4; ++j) {
                bh[j] = *(const bf16x8*)&bsh[sw8(j * 16 + l15, c)];
                if (!isv) bl[j] = *(const bf16x8*)&bsl[sw8(j * 16 + l15, c)];
            }
            #pragma unroll
            for (int i = 0; i < 2; ++i)
                #pragma unroll
                for (int j = 0; j < 4; ++j) {
                    acc[i][j] = MFMA(ah[i], bh[j], acc[i][j]);
                    if (!isv) {
                        acc[i][j] = MFMA(ah[i], bl[j], acc[i][j]);
                        acc[i][j] = MFMA(al[i], bh[j], acc[i][j]);
                    }
                }
        }
    }

    if (isv) {
        #pragma unroll
        for (int j = 0; j < 4; ++j) {
            const int e = j * 16 + l15;
            #pragma unroll
            for (int i = 0; i < 2; ++i) {
                const int nb = n0 + wvi * 32 + i * 16 + quad * 4;
                union { fp16v2 h; unsigned int u; } c01, c23;
                c01.h = __builtin_amdgcn_cvt_pkrtz(acc[i][j][0], acc[i][j][1]);
                c23.h = __builtin_amdgcn_cvt_pkrtz(acc[i][j][2], acc[i][j][3]);
                uint2 pk = {c01.u, c23.u};
                *(uint2*)&Vt[((size_t)hh * 64 + e) * N + nb] = pk;
            }
        }
    } else {
        // Q: fold 0.125 (1/sqrt(64)) * log2(e) so softmax runs in base 2.
        const float scale = (sec == 0) ? 0.125f * 1.44269504f : 1.0f;
        unsigned short* Oh = (sec == 0) ? Qh : Kh;
        unsigned short* Ol = (sec == 0) ? Ql : Kl;
        #pragma unroll
        for (int j = 0; j < 4; ++j) {
            const int e = j * 16 + l15;
            #pragma unroll
            for (int i = 0; i < 2; ++i)
                #pragma unroll
                for (int r = 0; r < 4; ++r) {
                    const int n = n0 + wvi * 32 + i * 16 + quad * 4 + r;
                    const float val = acc[i][j][r] * scale;
                    const unsigned short hv = f2bf(val);
                    Oh[((size_t)hh * N + n) * E + e] = hv;
                    Ol[((size_t)hh * N + n) * E + e] = f2bf(val - bf2f(hv));
                }
        }
    }
}

// ---------------------------------------------------------------------------
// K3: flash attention. R7 structure (128-key tiles, single buffer) with
// fp16 V/P and base-2 softmax. grid (32, 16); block 256 = 4 waves.
// ---------------------------------------------------------------------------
__global__ __launch_bounds__(256, 2) void attn_kernel(
    const unsigned short* __restrict__ Qh, const unsigned short* __restrict__ Ql,
    const unsigned short* __restrict__ Kh, const unsigned short* __restrict__ Kl,
    const unsigned short* __restrict__ Vt,   // fp16 [h*64+e][n]
    unsigned short* __restrict__ Ch)
{
    __shared__ unsigned short ksh[128 * 64], ksl[128 * 64];  // bf16 [key][e]
    __shared__ unsigned short vts[64 * 128];                 // fp16 [e][key]
    __shared__ unsigned short ps[4 * 16 * 136];              // fp16 P, padded
    const int r0 = blockIdx.x * 64, h = blockIdx.y;
    const int t = threadIdx.x, lane = t & 63, wvi = t >> 6, quad = lane >> 4, l15 = lane & 15;

    bf16x8 qfh[2], qfl[2];
    {
        const size_t base = ((size_t)h * N + r0 + wvi * 16 + l15) * E;
        #pragma unroll
        for (int kwi = 0; kwi < 2; ++kwi) {
            qfh[kwi] = *(const bf16x8*)&Qh[base + kwi * 32 + quad * 8];
            qfl[kwi] = *(const bf16x8*)&Ql[base + kwi * 32 + quad * 8];
        }
    }

    f32x4 oacc[4];
    #pragma unroll
    for (int ct = 0; ct < 4; ++ct) oacc[ct] = (f32x4){0.f, 0.f, 0.f, 0.f};
    float mrow[4] = {-1e30f, -1e30f, -1e30f, -1e30f};
    float lrow[4] = {0.f, 0.f, 0.f, 0.f};

    for (int m0 = 0; m0 < N; m0 += 128) {
        __syncthreads();
        #pragma unroll
        for (int p = 0; p < 4; ++p) {
            const int row = p * 32 + wvi * 8 + (lane >> 3);
            const int lc = (lane & 7) ^ (row & 7);
            const int lo = p * 2048 + wvi * 512 + lane * 8;
            const size_t gk = ((size_t)h * N + m0 + row) * E + lc * 8;
            dma16(&Kh[gk], &ksh[lo]);
            dma16(&Kl[gk], &ksl[lo]);
        }
        #pragma unroll
        for (int p = 0; p < 4; ++p) {
            const int row = p * 16 + wvi * 4 + (lane >> 4);
            const int lc = (lane & 15) ^ (row & 7);
            const int lo = p * 2048 + wvi * 512 + lane * 8;
            dma16(&Vt[((size_t)h * 64 + row) * N + m0 + lc * 8], &vts[lo]);
        }
        __syncthreads();

        // S = Q K^T (log2-domain scale folded into Q)
        f32x4 s[8];
        #pragma unroll
        for (int ct = 0; ct < 8; ++ct) s[ct] = (f32x4){0.f, 0.f, 0.f, 0.f};
        #pragma unroll
        for (int kwi = 0; kwi < 2; ++kwi) {
            const int c = kwi * 4 + quad;
            #pragma unroll
            for (int ct = 0; ct < 8; ++ct) {
                const bf16x8 bh = *(const bf16x8*)&ksh[sw8(ct * 16 + l15, c)];
                const bf16x8 bl = *(const bf16x8*)&ksl[sw8(ct * 16 + l15, c)];
                s[ct] = MFMA(qfh[kwi], bh, s[ct]);
                s[ct] = MFMA(qfh[kwi], bl, s[ct]);
                s[ct] = MFMA(qfl[kwi], bh, s[ct]);
            }
        }

        // online softmax (base 2)
        #pragma unroll
        for (int r = 0; r < 4; ++r) {
            float mx = s[0][r];
            #pragma unroll
            for (int ct = 1; ct < 8; ++ct) mx = fmaxf(mx, s[ct][r]);
            mx = fmaxf(mx, __shfl_xor(mx, 1));
            mx = fmaxf(mx, __shfl_xor(mx, 2));
            mx = fmaxf(mx, __shfl_xor(mx, 4));
            mx = fmaxf(mx, __shfl_xor(mx, 8));
            const float mn = fmaxf(mrow[r], mx);
            const float alpha = exp2f(mrow[r] - mn);
            mrow[r] = mn;
            float sum = 0.f;
            #pragma unroll
            for (int ct = 0; ct < 8; ++ct) {
                const float p = exp2f(s[ct][r] - mn);
                s[ct][r] = p;
                sum += p;
            }
            sum += __shfl_xor(sum, 1);
            sum += __shfl_xor(sum, 2);
            sum += __shfl_xor(sum, 4);
            sum += __shfl_xor(sum, 8);
            lrow[r] = lrow[r] * alpha + sum;
            #pragma unroll
            for (int ct = 0; ct < 4; ++ct) oacc[ct][r] *= alpha;
        }

        // P -> wave-private LDS as fp16 (C-layout -> A-layout)
        #pragma unroll
        for (int ct = 0; ct < 8; ++ct)
            #pragma unroll
            for (int r = 0; r < 4; ++r) {
                union { _Float16 h; unsigned short u; } cv;
                cv.h = (_Float16)s[ct][r];
                ps[(wvi * 16 + quad * 4 + r) * 136 + ct * 16 + l15] = cv.u;
            }

        // O += P V (fp16 MFMA)
        #pragma unroll
        for (int kwi = 0; kwi < 4; ++kwi) {
            const f16x8 pa = *(const f16x8*)&ps[(wvi * 16 + l15) * 136 + kwi * 32 + quad * 8];
            #pragma unroll
            for (int ct = 0; ct < 4; ++ct) {
                const f16x8 vb = *(const f16x8*)&vts[sw16(ct * 16 + l15, kwi * 4 + quad)];
                oacc[ct] = MFMAH(pa, vb, oacc[ct]);
            }
        }
    }

    #pragma unroll
    for (int r = 0; r < 4; ++r) {
        const float inv = 1.f / lrow[r];
        const int n = r0 + wvi * 16 + quad * 4 + r;
        #pragma unroll
        for (int ct = 0; ct < 4; ++ct)
            Ch[(size_t)n * D + h * 64 + ct * 16 + l15] = f2bf(oacc[ct][r] * inv);
    }
}

// ---------------------------------------------------------------------------
// K4: out = ctx @ Wo, single-term bf16. grid (32, 16); tile 64x64, BK=64.
// ---------------------------------------------------------------------------
__global__ __launch_bounds__(256, 4) void out_proj_kernel(
    const unsigned short* __restrict__ Chh, const unsigned short* __restrict__ Wh,
    float* __restrict__ out)
{
    __shared__ unsigned short ash[64 * 64], bsh[64 * 64];
    const int n0 = blockIdx.x * 64, c0 = blockIdx.y * 64;
    const int t = threadIdx.x, lane = t & 63, wvi = t >> 6, quad = lane >> 4, l15 = lane & 15;

    f32x4 acc[4];
    #pragma unroll
    for (int j = 0; j < 4; ++j) acc[j] = (f32x4){0.f, 0.f, 0.f, 0.f};

    for (int k0 = 0; k0 < D; k0 += 64) {
        __syncthreads();
        #pragma unroll
        for (int p = 0; p < 2; ++p) {
            const int row = p * 32 + wvi * 8 + (lane >> 3);
            const int lc = (lane & 7) ^ (row & 7);
            const int lo = p * 2048 + wvi * 512 + lane * 8;
            dma16(&Chh[(size_t)(n0 + row) * D + k0 + lc * 8], &ash[lo]);
            dma16(&Wh[(size_t)(c0 + row) * D + k0 + lc * 8], &bsh[lo]);
        }
        __syncthreads();

        #pragma unroll
        for (int kwi = 0; kwi < 2; ++kwi) {
            const int c = kwi * 4 + quad;
            const bf16x8 ah = *(const bf16x8*)&ash[sw8(wvi * 16 + l15, c)];
            #pragma unroll
            for (int j = 0; j < 4; ++j) {
                const bf16x8 bh = *(const bf16x8*)&bsh[sw8(j * 16 + l15, c)];
                acc[j] = MFMA(ah, bh, acc[j]);
            }
        }
    }

    #pragma unroll
    for (int r = 0; r < 4; ++r) {
        const int n = n0 + wvi * 16 + quad * 4 + r;
        #pragma unroll
        for (int j = 0; j < 4; ++j)
            out[(size_t)n * D + c0 + j * 16 + l15] = acc[j][r];
    }
}

// ---------------------------------------------------------------------------
extern "C" void kernel_launch(void* const* d_in, const int* in_sizes, int n_in,
                              void* d_out, int out_size, void* d_ws, size_t ws_size,
                              hipStream_t stream) {
    const float* x  = (const float*)d_in[0];
    const float* qw = (const float*)d_in[1];
    const float* kw = (const float*)d_in[2];
    const float* vw = (const float*)d_in[3];
    const float* ow = (const float*)d_in[4];
    float* out = (float*)d_out;

    unsigned short* ws = (unsigned short*)d_ws;
    const size_t M1 = 1024 * 1024;
    unsigned short* wBh = ws;                 // [2048][1024] = 2M shorts
    unsigned short* wBl = ws + 2 * M1;
    unsigned short* wvt = ws + 4 * M1;        // [1024][1024] = 1M
    unsigned short* woh = ws + 5 * M1;
    unsigned short* xh  = ws + 6 * M1;        // [2048][1024] = 2M
    unsigned short* xl  = ws + 8 * M1;
    unsigned short* Qh  = ws + 10 * M1;       // [h][n][e] = 2M each
    unsigned short* Ql  = ws + 12 * M1;
    unsigned short* Kh  = ws + 14 * M1;
    unsigned short* Kl  = ws + 16 * M1;
    unsigned short* Vt  = ws + 18 * M1;       // fp16 [h*64+e][n] = 2M
    unsigned short* Ch  = xh;                 // alias: x dead after qkv

    convert_all_kernel<<<3072, 256, 0, stream>>>(x, qw, kw, vw, ow,
                                                 xh, xl, wBh, wBl, wvt, woh);
    qkv_kernel<<<dim3(16, 48), 256, 0, stream>>>(xh, xl, wBh, wBl, wvt,
                                                 Qh, Ql, Kh, Kl, Vt);
    attn_kernel<<<dim3(32, 16), 256, 0, stream>>>(Qh, Ql, Kh, Kl, Vt, Ch);
    out_proj_kernel<<<dim3(32, 16), 256, 0, stream>>>(Ch, woh, out);
}

// Round 12
// 188.438 us; speedup vs baseline: 1.0509x; 1.0171x over previous
//
#include <hip/hip_runtime.h>

#define H 16
#define N 2048
#define E 64
#define D 1024

typedef __attribute__((ext_vector_type(8))) short bf16x8;
typedef __attribute__((ext_vector_type(8))) _Float16 f16x8;
typedef __attribute__((ext_vector_type(2))) __fp16 fp16v2;
typedef __attribute__((ext_vector_type(4))) float f32x4;

__device__ __forceinline__ float bf2f(unsigned short u) {
    union { unsigned int i; float f; } v;
    v.i = ((unsigned int)u) << 16;
    return v.f;
}
__device__ __forceinline__ unsigned short f2bf(float f) {
    unsigned int u = __float_as_uint(f);
    return (unsigned short)((u + 0x7fffu + ((u >> 16) & 1u)) >> 16);
}
#define MFMA(a, b, c)  __builtin_amdgcn_mfma_f32_16x16x32_bf16(a, b, c, 0, 0, 0)
#define MFMAH(a, b, c) __builtin_amdgcn_mfma_f32_16x16x32_f16(a, b, c, 0, 0, 0)

// async global->LDS, 16B per lane. LDS dest must be base+lane*16 contiguous.
typedef __attribute__((address_space(3))) unsigned int lds_u32;
typedef const __attribute__((address_space(1))) unsigned int glb_u32;
__device__ __forceinline__ void dma16(const unsigned short* g, unsigned short* l) {
    __builtin_amdgcn_global_load_lds((glb_u32*)g, (lds_u32*)l, 16, 0, 0);
}

// XOR-swizzled LDS tiles (16B chunk granularity): physical chunk = c ^ (row&7).
__device__ __forceinline__ int sw8(int row, int c)  { return row * 64  + ((c ^ (row & 7)) << 3); }
__device__ __forceinline__ int sw16(int row, int c) { return row * 128 + ((c ^ (row & 7)) << 3); }

// ---------------------------------------------------------------------------
// K1: merged converts. blocks [0,2048): x fp32 -> xh/xl.
// blocks [2048,3072): weights. q -> wBh/wBl rows [0,1024); k -> rows
// [1024,2048); v -> wvt [h*64+e][d] (hi only); o -> woh [c][d] (hi only).
// ---------------------------------------------------------------------------
__global__ __launch_bounds__(256) void convert_all_kernel(
    const float* __restrict__ x,
    const float* __restrict__ qw, const float* __restrict__ kw,
    const float* __restrict__ vw, const float* __restrict__ ow,
    unsigned short* __restrict__ xh, unsigned short* __restrict__ xl,
    unsigned short* __restrict__ wBh, unsigned short* __restrict__ wBl,
    unsigned short* __restrict__ wvt, unsigned short* __restrict__ woh)
{
    __shared__ float ts[64][65];
    const int b0 = blockIdx.x;
    const int t = threadIdx.x;
    if (b0 < 2048) {
        const int i = (b0 * 256 + t) * 4;
        const float4 v = *(const float4*)&x[i];
        ushort4 hh, ll;
        hh.x = f2bf(v.x); ll.x = f2bf(v.x - bf2f(hh.x));
        hh.y = f2bf(v.y); ll.y = f2bf(v.y - bf2f(hh.y));
        hh.z = f2bf(v.z); ll.z = f2bf(v.z - bf2f(hh.z));
        hh.w = f2bf(v.w); ll.w = f2bf(v.w - bf2f(hh.w));
        *(ushort4*)&xh[i] = hh;
        *(ushort4*)&xl[i] = ll;
        return;
    }
    const int b = b0 - 2048;
    const float* src;
    int rs, dt, orow0;
    bool has_lo;
    unsigned short *dh, *dl;
    if (b < 768) {
        const int which = b >> 8, r = b & 255, h = r >> 4;
        dt = r & 15;
        src = (which == 0 ? qw : which == 1 ? kw : vw) + ((size_t)h * D + dt * 64) * E;
        rs = E;
        if (which == 0)      { dh = wBh; dl = wBl; orow0 = h * 64;        has_lo = true; }
        else if (which == 1) { dh = wBh; dl = wBl; orow0 = 1024 + h * 64; has_lo = true; }
        else                 { dh = wvt; dl = wBl; orow0 = h * 64;        has_lo = false; }
    } else {
        const int r = b - 768, ct = r >> 4;
        dt = r & 15;
        src = ow + (size_t)(dt * 64) * D + ct * 64;
        rs = D;
        orow0 = ct * 64;
        dh = woh; dl = wBl; has_lo = false;   // o: hi only
    }
    {
        const int row = t >> 2, cb = (t & 3) * 16;
        #pragma unroll
        for (int j = 0; j < 16; j += 4) {
            const float4 v = *(const float4*)&src[row * rs + cb + j];
            ts[row][cb + j + 0] = v.x;
            ts[row][cb + j + 1] = v.y;
            ts[row][cb + j + 2] = v.z;
            ts[row][cb + j + 3] = v.w;
        }
    }
    __syncthreads();
    {
        const int cl = t >> 2, dp = (t & 3) * 16;
        bf16x8 hv0, hv1, lv0, lv1;
        #pragma unroll
        for (int i = 0; i < 16; ++i) {
            const float f = ts[dp + i][cl];
            const unsigned short hh = f2bf(f);
            const unsigned short lo = f2bf(f - bf2f(hh));
            if (i < 8) { hv0[i] = (short)hh; lv0[i] = (short)lo; }
            else       { hv1[i - 8] = (short)hh; lv1[i - 8] = (short)lo; }
        }
        const size_t o = (size_t)(orow0 + cl) * D + dt * 64 + dp;
        *(bf16x8*)&dh[o] = hv0;
        *(bf16x8*)&dh[o + 8] = hv1;
        if (has_lo) {
            *(bf16x8*)&dl[o] = lv0;
            *(bf16x8*)&dl[o + 8] = lv1;
        }
    }
}

// ---------------------------------------------------------------------------
// K2: QKV projection. grid (16 Mtiles, 48 col-tiles); 128x64 tiles, BK=64.
// [0,16)=Q, [16,32)=K, [32,48)=V. Q scaled by 0.125*log2(e) (base-2 softmax).
// Q/K stored bf16 hi/lo (3-term QK numerics — R11 showed fp16-single K fails).
// Vt output is fp16 [h*64+e][n].
// ---------------------------------------------------------------------------
__global__ __launch_bounds__(256, 3) void qkv_kernel(
    const unsigned short* __restrict__ xh, const unsigned short* __restrict__ xl,
    const unsigned short* __restrict__ wBh, const unsigned short* __restrict__ wBl,
    const unsigned short* __restrict__ wvt,
    unsigned short* __restrict__ Qh, unsigned short* __restrict__ Ql,
    unsigned short* __restrict__ Kh, unsigned short* __restrict__ Kl,
    unsigned short* __restrict__ Vt)
{
    __shared__ unsigned short ash[128 * 64], asl[128 * 64];
    __shared__ unsigned short bsh[64 * 64], bsl[64 * 64];
    const int n0 = blockIdx.x * 128;
    const int ct0 = blockIdx.y;
    const int sec = ct0 >> 4;            // 0=Q 1=K 2=V
    const int hh = ct0 & 15;
    const bool isv = (sec == 2);
    const unsigned short* Bh = isv ? wvt : wBh;
    const size_t brow0 = (sec == 1 ? 1024 : 0) + hh * 64;

    const int t = threadIdx.x;
    const int lane = t & 63, wvi = t >> 6, quad = lane >> 4, l15 = lane & 15;

    f32x4 acc[2][4];
    #pragma unroll
    for (int i = 0; i < 2; ++i)
        #pragma unroll
        for (int j = 0; j < 4; ++j) acc[i][j] = (f32x4){0.f, 0.f, 0.f, 0.f};

    for (int k0 = 0; k0 < D; k0 += 64) {
        __syncthreads();
        #pragma unroll
        for (int p = 0; p < 4; ++p) {
            const int row = p * 32 + wvi * 8 + (lane >> 3);
            const int lc = (lane & 7) ^ (row & 7);
            const int lo = p * 2048 + wvi * 512 + lane * 8;
            const size_t ga = (size_t)(n0 + row) * D + k0 + lc * 8;
            dma16(&xh[ga], &ash[lo]);
            if (!isv) dma16(&xl[ga], &asl[lo]);
        }
        #pragma unroll
        for (int p = 0; p < 2; ++p) {
            const int row = p * 32 + wvi * 8 + (lane >> 3);
            const int lc = (lane & 7) ^ (row & 7);
            const int lo = p * 2048 + wvi * 512 + lane * 8;
            const size_t gb = (brow0 + row) * D + k0 + lc * 8;
            dma16(&Bh[gb], &bsh[lo]);
            if (!isv) dma16(&wBl[gb], &bsl[lo]);
        }
        __syncthreads();

        #pragma unroll
        for (int kwi = 0; kwi < 2; ++kwi) {
            const int c = kwi * 4 + quad;
            bf16x8 ah[2], al[2], bh[4], bl[4];
            #pragma unroll
            for (int i = 0; i < 2; ++i) {
                ah[i] = *(const bf16x8*)&ash[sw8(wvi * 32 + i * 16 + l15, c)];
                if (!isv) al[i] = *(const bf16x8*)&asl[sw8(wvi * 32 + i * 16 + l15, c)];
            }
            #pragma unroll
            for (int j = 0; j < 4; ++j) {
                bh[j] = *(const bf16x8*)&bsh[sw8(j * 16 + l15, c)];
                if (!isv) bl[j] = *(const bf16x8*)&bsl[sw8(j * 16 + l15, c)];
            }
            #pragma unroll
            for (int i = 0; i < 2; ++i)
                #pragma unroll
                for (int j = 0; j < 4; ++j) {
                    acc[i][j] = MFMA(ah[i], bh[j], acc[i][j]);
                    if (!isv) {
                        acc[i][j] = MFMA(ah[i], bl[j], acc[i][j]);
                        acc[i][j] = MFMA(al[i], bh[j], acc[i][j]);
                    }
                }
        }
    }

    if (isv) {
        #pragma unroll
        for (int j = 0; j < 4; ++j) {
            const int e = j * 16 + l15;
            #pragma unroll
            for (int i = 0; i < 2; ++i) {
                const int nb = n0 + wvi * 32 + i * 16 + quad * 4;
                union { fp16v2 h; unsigned int u; } c01, c23;
                c01.h = __builtin_amdgcn_cvt_pkrtz(acc[i][j][0], acc[i][j][1]);
                c23.h = __builtin_amdgcn_cvt_pkrtz(acc[i][j][2], acc[i][j][3]);
                uint2 pk = {c01.u, c23.u};
                *(uint2*)&Vt[((size_t)hh * 64 + e) * N + nb] = pk;
            }
        }
    } else {
        // Q: fold 0.125 (1/sqrt(64)) * log2(e) so softmax runs in base 2.
        const float scale = (sec == 0) ? 0.125f * 1.44269504f : 1.0f;
        unsigned short* Oh = (sec == 0) ? Qh : Kh;
        unsigned short* Ol = (sec == 0) ? Ql : Kl;
        #pragma unroll
        for (int j = 0; j < 4; ++j) {
            const int e = j * 16 + l15;
            #pragma unroll
            for (int i = 0; i < 2; ++i)
                #pragma unroll
                for (int r = 0; r < 4; ++r) {
                    const int n = n0 + wvi * 32 + i * 16 + quad * 4 + r;
                    const float val = acc[i][j][r] * scale;
                    const unsigned short hv = f2bf(val);
                    Oh[((size_t)hh * N + n) * E + e] = hv;
                    Ol[((size_t)hh * N + n) * E + e] = f2bf(val - bf2f(hv));
                }
        }
    }
}

// ---------------------------------------------------------------------------
// K3: flash attention. 128-key tiles, single buffer, fp16 V/P, base-2
// softmax, 3-term bf16 QK. Phase stagger keyed on (bx+by)&15 so co-resident
// blocks (flat idx i and i+256: same bx, by+8) run half-period apart.
// grid (32, 16); block 256 = 4 waves.
// ---------------------------------------------------------------------------
__global__ __launch_bounds__(256, 2) void attn_kernel(
    const unsigned short* __restrict__ Qh, const unsigned short* __restrict__ Ql,
    const unsigned short* __restrict__ Kh, const unsigned short* __restrict__ Kl,
    const unsigned short* __restrict__ Vt,   // fp16 [h*64+e][n]
    unsigned short* __restrict__ Ch)
{
    __shared__ unsigned short ksh[128 * 64], ksl[128 * 64];  // bf16 [key][e]
    __shared__ unsigned short vts[64 * 128];                 // fp16 [e][key]
    __shared__ unsigned short ps[4 * 16 * 136];              // fp16 P, padded
    const int r0 = blockIdx.x * 64, h = blockIdx.y;
    const int t = threadIdx.x, lane = t & 63, wvi = t >> 6, quad = lane >> 4, l15 = lane & 15;

    bf16x8 qfh[2], qfl[2];
    {
        const size_t base = ((size_t)h * N + r0 + wvi * 16 + l15) * E;
        #pragma unroll
        for (int kwi = 0; kwi < 2; ++kwi) {
            qfh[kwi] = *(const bf16x8*)&Qh[base + kwi * 32 + quad * 8];
            qfl[kwi] = *(const bf16x8*)&Ql[base + kwi * 32 + quad * 8];
        }
    }

    f32x4 oacc[4];
    #pragma unroll
    for (int ct = 0; ct < 4; ++ct) oacc[ct] = (f32x4){0.f, 0.f, 0.f, 0.f};
    float mrow[4] = {-1e30f, -1e30f, -1e30f, -1e30f};
    float lrow[4] = {0.f, 0.f, 0.f, 0.f};

    const int tb = (blockIdx.x + blockIdx.y) & 15;
    for (int it = 0; it < 16; ++it) {
        const int m0 = ((tb + it) & 15) << 7;
        __syncthreads();
        #pragma unroll
        for (int p = 0; p < 4; ++p) {
            const int row = p * 32 + wvi * 8 + (lane >> 3);
            const int lc = (lane & 7) ^ (row & 7);
            const int lo = p * 2048 + wvi * 512 + lane * 8;
            const size_t gk = ((size_t)h * N + m0 + row) * E + lc * 8;
            dma16(&Kh[gk], &ksh[lo]);
            dma16(&Kl[gk], &ksl[lo]);
        }
        #pragma unroll
        for (int p = 0; p < 4; ++p) {
            const int row = p * 16 + wvi * 4 + (lane >> 4);
            const int lc = (lane & 15) ^ (row & 7);
            const int lo = p * 2048 + wvi * 512 + lane * 8;
            dma16(&Vt[((size_t)h * 64 + row) * N + m0 + lc * 8], &vts[lo]);
        }
        __syncthreads();

        // S = Q K^T (log2-domain scale folded into Q)
        f32x4 s[8];
        #pragma unroll
        for (int ct = 0; ct < 8; ++ct) s[ct] = (f32x4){0.f, 0.f, 0.f, 0.f};
        #pragma unroll
        for (int kwi = 0; kwi < 2; ++kwi) {
            const int c = kwi * 4 + quad;
            #pragma unroll
            for (int ct = 0; ct < 8; ++ct) {
                const bf16x8 bh = *(const bf16x8*)&ksh[sw8(ct * 16 + l15, c)];
                const bf16x8 bl = *(const bf16x8*)&ksl[sw8(ct * 16 + l15, c)];
                s[ct] = MFMA(qfh[kwi], bh, s[ct]);
                s[ct] = MFMA(qfh[kwi], bl, s[ct]);
                s[ct] = MFMA(qfl[kwi], bh, s[ct]);
            }
        }

        // online softmax (base 2)
        #pragma unroll
        for (int r = 0; r < 4; ++r) {
            float mx = s[0][r];
            #pragma unroll
            for (int ct = 1; ct < 8; ++ct) mx = fmaxf(mx, s[ct][r]);
            mx = fmaxf(mx, __shfl_xor(mx, 1));
            mx = fmaxf(mx, __shfl_xor(mx, 2));
            mx = fmaxf(mx, __shfl_xor(mx, 4));
            mx = fmaxf(mx, __shfl_xor(mx, 8));
            const float mn = fmaxf(mrow[r], mx);
            const float alpha = exp2f(mrow[r] - mn);
            mrow[r] = mn;
            float sum = 0.f;
            #pragma unroll
            for (int ct = 0; ct < 8; ++ct) {
                const float p = exp2f(s[ct][r] - mn);
                s[ct][r] = p;
                sum += p;
            }
            sum += __shfl_xor(sum, 1);
            sum += __shfl_xor(sum, 2);
            sum += __shfl_xor(sum, 4);
            sum += __shfl_xor(sum, 8);
            lrow[r] = lrow[r] * alpha + sum;
            #pragma unroll
            for (int ct = 0; ct < 4; ++ct) oacc[ct][r] *= alpha;
        }

        // P -> wave-private LDS as fp16 (C-layout -> A-layout)
        #pragma unroll
        for (int ct = 0; ct < 8; ++ct)
            #pragma unroll
            for (int r = 0; r < 4; ++r) {
                union { _Float16 h; unsigned short u; } cv;
                cv.h = (_Float16)s[ct][r];
                ps[(wvi * 16 + quad * 4 + r) * 136 + ct * 16 + l15] = cv.u;
            }

        // O += P V (fp16 MFMA)
        #pragma unroll
        for (int kwi = 0; kwi < 4; ++kwi) {
            const f16x8 pa = *(const f16x8*)&ps[(wvi * 16 + l15) * 136 + kwi * 32 + quad * 8];
            #pragma unroll
            for (int ct = 0; ct < 4; ++ct) {
                const f16x8 vb = *(const f16x8*)&vts[sw16(ct * 16 + l15, kwi * 4 + quad)];
                oacc[ct] = MFMAH(pa, vb, oacc[ct]);
            }
        }
    }

    #pragma unroll
    for (int r = 0; r < 4; ++r) {
        const float inv = 1.f / lrow[r];
        const int n = r0 + wvi * 16 + quad * 4 + r;
        #pragma unroll
        for (int ct = 0; ct < 4; ++ct)
            Ch[(size_t)n * D + h * 64 + ct * 16 + l15] = f2bf(oacc[ct][r] * inv);
    }
}

// ---------------------------------------------------------------------------
// K4: out = ctx @ Wo, single-term bf16. grid (32, 16); tile 64x64, BK=64.
// ---------------------------------------------------------------------------
__global__ __launch_bounds__(256, 4) void out_proj_kernel(
    const unsigned short* __restrict__ Chh, const unsigned short* __restrict__ Wh,
    float* __restrict__ out)
{
    __shared__ unsigned short ash[64 * 64], bsh[64 * 64];
    const int n0 = blockIdx.x * 64, c0 = blockIdx.y * 64;
    const int t = threadIdx.x, lane = t & 63, wvi = t >> 6, quad = lane >> 4, l15 = lane & 15;

    f32x4 acc[4];
    #pragma unroll
    for (int j = 0; j < 4; ++j) acc[j] = (f32x4){0.f, 0.f, 0.f, 0.f};

    for (int k0 = 0; k0 < D; k0 += 64) {
        __syncthreads();
        #pragma unroll
        for (int p = 0; p < 2; ++p) {
            const int row = p * 32 + wvi * 8 + (lane >> 3);
            const int lc = (lane & 7) ^ (row & 7);
            const int lo = p * 2048 + wvi * 512 + lane * 8;
            dma16(&Chh[(size_t)(n0 + row) * D + k0 + lc * 8], &ash[lo]);
            dma16(&Wh[(size_t)(c0 + row) * D + k0 + lc * 8], &bsh[lo]);
        }
        __syncthreads();

        #pragma unroll
        for (int kwi = 0; kwi < 2; ++kwi) {
            const int c = kwi * 4 + quad;
            const bf16x8 ah = *(const bf16x8*)&ash[sw8(wvi * 16 + l15, c)];
            #pragma unroll
            for (int j = 0; j < 4; ++j) {
                const bf16x8 bh = *(const bf16x8*)&bsh[sw8(j * 16 + l15, c)];
                acc[j] = MFMA(ah, bh, acc[j]);
            }
        }
    }

    #pragma unroll
    for (int r = 0; r < 4; ++r) {
        const int n = n0 + wvi * 16 + quad * 4 + r;
        #pragma unroll
        for (int j = 0; j < 4; ++j)
            out[(size_t)n * D + c0 + j * 16 + l15] = acc[j][r];
    }
}

// ---------------------------------------------------------------------------
extern "C" void kernel_launch(void* const* d_in, const int* in_sizes, int n_in,
                              void* d_out, int out_size, void* d_ws, size_t ws_size,
                              hipStream_t stream) {
    const float* x  = (const float*)d_in[0];
    const float* qw = (const float*)d_in[1];
    const float* kw = (const float*)d_in[2];
    const float* vw = (const float*)d_in[3];
    const float* ow = (const float*)d_in[4];
    float* out = (float*)d_out;

    unsigned short* ws = (unsigned short*)d_ws;
    const size_t M1 = 1024 * 1024;
    unsigned short* wBh = ws;                 // [2048][1024] = 2M shorts
    unsigned short* wBl = ws + 2 * M1;
    unsigned short* wvt = ws + 4 * M1;        // [1024][1024] = 1M
    unsigned short* woh = ws + 5 * M1;
    unsigned short* xh  = ws + 6 * M1;        // [2048][1024] = 2M
    unsigned short* xl  = ws + 8 * M1;
    unsigned short* Qh  = ws + 10 * M1;       // bf16 [h][n][e] = 2M each
    unsigned short* Ql  = ws + 12 * M1;
    unsigned short* Kh  = ws + 14 * M1;
    unsigned short* Kl  = ws + 16 * M1;
    unsigned short* Vt  = ws + 18 * M1;       // fp16 [h*64+e][n] = 2M
    unsigned short* Ch  = xh;                 // alias: x dead after qkv

    convert_all_kernel<<<3072, 256, 0, stream>>>(x, qw, kw, vw, ow,
                                                 xh, xl, wBh, wBl, wvt, woh);
    qkv_kernel<<<dim3(16, 48), 256, 0, stream>>>(xh, xl, wBh, wBl, wvt,
                                                 Qh, Ql, Kh, Kl, Vt);
    attn_kernel<<<dim3(32, 16), 256, 0, stream>>>(Qh, Ql, Kh, Kl, Vt, Ch);
    out_proj_kernel<<<dim3(32, 16), 256, 0, stream>>>(Ch, woh, out);
}